// Round 1
// baseline (244.496 us; speedup 1.0000x reference)
//
#include <hip/hip_runtime.h>
#include <hip/hip_bf16.h>

typedef unsigned short u16;
typedef unsigned int u32;
typedef __attribute__((ext_vector_type(8))) short short8;
typedef __attribute__((ext_vector_type(4))) float floatx4;
typedef __attribute__((ext_vector_type(4))) u32 uint4v;

__device__ __forceinline__ u16 f32_to_bf16_rne(float f) {
  union { float f; unsigned int u; } v; v.f = f;
  unsigned int u = v.u;
  u += 0x7FFFu + ((u >> 16) & 1u);
  return (u16)(u >> 16);
}

__device__ __forceinline__ void load_lds_16(const void* gsrc, void* lds) {
  __builtin_amdgcn_global_load_lds(
      (const __attribute__((address_space(1))) unsigned int*)gsrc,
      (__attribute__((address_space(3))) unsigned int*)lds,
      16, 0, 0);
}

// ============================================================================
// NEW PATH
// ============================================================================

// ---- Kernel 1: fused transpose(+bf16 cvt) + partial pool --------------------
// grid (49, 32), 256 threads. Block owns 64 n-columns of one batch b.
// Writes xT[b][n][c] bf16 (51.4 MB) and pp[b][nb][c] (per-block n-partial sums).
__global__ __launch_bounds__(256) void transpose_pool_kernel(
    const float* __restrict__ x, u16* __restrict__ xT, float* __restrict__ pp) {
  const int nb = blockIdx.x;        // n-tile 0..48
  const int b  = blockIdx.y;        // 0..31
  const int t  = threadIdx.x;
  const int l  = t & 15;            // float4 index along n
  const int r  = t >> 4;            // c row slot 0..15
  const int n0 = nb * 64;

  // pitch 66 u16 (132 B): b16 transpose-writes 2-way (free), b32 reads conflict-free
  __shared__ __align__(16) u16 T[64][66];
  __shared__ float poolacc[256];

  const float* xb = x + (size_t)b * (256 * 3136);
  u16* xTb = xT + ((size_t)b * 3136 + n0) * 256;

  for (int cc = 0; cc < 4; ++cc) {
    // read 64 c-rows x 64 n (coalesced f32), cvt, transpose into LDS
    #pragma unroll
    for (int j = 0; j < 4; ++j) {
      const int c_local = j * 16 + r;                  // 0..63
      const int c = cc * 64 + c_local;                 // 0..255 (each c touched once)
      float4 v = *(const float4*)(xb + (size_t)c * 3136 + n0 + l * 4);
      // pool partial over this block's 64 n for channel c (quarter-wave reduce)
      float s = (v.x + v.y) + (v.z + v.w);
      s += __shfl_down(s, 8, 16);
      s += __shfl_down(s, 4, 16);
      s += __shfl_down(s, 2, 16);
      s += __shfl_down(s, 1, 16);
      if (l == 0) poolacc[c] = s;
      T[l * 4 + 0][c_local] = f32_to_bf16_rne(v.x);
      T[l * 4 + 1][c_local] = f32_to_bf16_rne(v.y);
      T[l * 4 + 2][c_local] = f32_to_bf16_rne(v.z);
      T[l * 4 + 3][c_local] = f32_to_bf16_rne(v.w);
    }
    __syncthreads();
    // write out 64 n-rows x 64 c bf16, coalesced 32 B/thread
    {
      const int nl = t >> 2;        // n row 0..63
      const int s4 = t & 3;         // 16-c segment 0..3
      u32 dw[8];
      #pragma unroll
      for (int u = 0; u < 8; ++u)
        dw[u] = *(const u32*)&T[nl][s4 * 16 + u * 2];
      u16* dst = xTb + (size_t)nl * 256 + cc * 64 + s4 * 16;
      *(uint4v*)dst       = (uint4v){dw[0], dw[1], dw[2], dw[3]};
      *(uint4v*)(dst + 8) = (uint4v){dw[4], dw[5], dw[6], dw[7]};
    }
    __syncthreads();   // protect T before next chunk overwrites
  }
  // all 256 poolacc entries written (one per (cc,j,r)); last barrier makes them visible
  pp[((size_t)b * 49 + nb) * 256 + t] = poolacc[t];
}

// ---- Kernel 2: attention MLP + w_dyn (bf16), pooled from partials -----------
__global__ __launch_bounds__(256) void attn_wdyn_kernel2(
    const float* __restrict__ pp, const float* __restrict__ weights,
    const float* __restrict__ w1, const float* __restrict__ b1,
    const float* __restrict__ w2, const float* __restrict__ b2,
    u16* __restrict__ wdyn) {
  const int blk = blockIdx.x;
  const int b = blk >> 3;
  const int oc = blk & 7;
  const int t = threadIdx.x;
  __shared__ float ph[256];
  __shared__ float part[256];
  __shared__ float hb[64];
  __shared__ float lg[8];
  // reduce 49 per-block partials -> pooled mean
  {
    float s = 0.0f;
    const float* pb = pp + (size_t)b * 49 * 256 + t;
    #pragma unroll 7
    for (int j = 0; j < 49; ++j) s += pb[j * 256];
    ph[t] = s * (1.0f / 3136.0f);
  }
  __syncthreads();
  {
    const int row = t >> 2, seg = t & 3;
    const float* wr = w1 + row * 256 + seg * 64;
    const float* ppx = ph + seg * 64;
    float a = 0.0f;
    #pragma unroll 8
    for (int c = 0; c < 64; ++c) a += ppx[c] * wr[c];
    part[t] = a;
  }
  __syncthreads();
  if (t < 64) {
    float a = part[t * 4] + part[t * 4 + 1] + part[t * 4 + 2] + part[t * 4 + 3] + b1[t];
    hb[t] = fmaxf(a, 0.0f);
  }
  __syncthreads();
  if (t < 64) {
    const int row = t >> 3, seg = t & 7;
    const float* wr = w2 + row * 64 + seg * 8;
    float a = 0.0f;
    #pragma unroll
    for (int j = 0; j < 8; ++j) a += hb[seg * 8 + j] * wr[j];
    part[t] = a;
  }
  __syncthreads();
  if (t < 8) {
    float a = b2[t];
    #pragma unroll
    for (int j = 0; j < 8; ++j) a += part[t * 8 + j];
    lg[t] = a;
  }
  __syncthreads();
  float a[8];
  {
    float mx = lg[0];
    #pragma unroll
    for (int e = 1; e < 8; ++e) mx = fmaxf(mx, lg[e]);
    float sum = 0.0f;
    #pragma unroll
    for (int e = 0; e < 8; ++e) { a[e] = __expf(lg[e] - mx); sum += a[e]; }
    float inv = 1.0f / sum;
    #pragma unroll
    for (int e = 0; e < 8; ++e) a[e] *= inv;
  }
  const int o0 = oc * 32;
  for (int i = 0; i < 32; ++i) {
    const int o = o0 + i;
    float acc = 0.0f;
    #pragma unroll
    for (int e = 0; e < 8; ++e)
      acc += a[e] * weights[((size_t)e * 256 + o) * 256 + t];
    wdyn[((size_t)b * 256 + o) * 256 + t] = f32_to_bf16_rne(acc);
  }
}

// ---- Kernel 3: batched GEMM, bf16 operands, double-buffered, swizzled LDS ---
// out[b] = Wdyn[b] @ X[b].  M=256, N=3136, K=256. Tile 256x64x32, 4 waves.
// Both operands staged via global_load_lds width=16 with XOR source-pre-swizzle:
// chunk (row, q) stored at (row, q ^ ((row>>1)&3)) -> frag ds_read_b128 is
// 2-way (free) instead of 8-way banked.
#define BM 256
#define BN 64
#define BK 32
#define XP 40

__global__ __launch_bounds__(256) void dynconv_gemm2(
    const u16* __restrict__ xT, const u16* __restrict__ wdyn,
    float* __restrict__ out) {
  const int nb = blockIdx.x;   // 0..48
  const int b  = blockIdx.y;   // 0..31
  const int t = threadIdx.x;
  const int lane = t & 63;
  const int wv = t >> 6;
  const int quad = lane >> 4;
  const int l16 = lane & 15;
  const int n0 = nb * BN;

  __shared__ __align__(16) u16 Ws[2][BM * BK];   // 2 x 16 KB
  __shared__ __align__(16) u16 Xs[2][BN * BK];   // 2 x 4 KB

  const u16* wb = wdyn + (size_t)b * 256 * 256;
  const u16* xn = xT + ((size_t)b * 3136 + n0) * 256;
  float* ob = out + (size_t)b * 256 * 3136 + n0;

  const int wq = (t & 3) ^ ((t >> 3) & 3);  // staging source-chunk swizzle
  const int rw = t >> 2;                    // row slot (W) / n (X), 0..63

  floatx4 acc[4][4];
  #pragma unroll
  for (int i = 0; i < 4; ++i)
    #pragma unroll
    for (int j = 0; j < 4; ++j) acc[i][j] = (floatx4)(0.0f);

  // stage K-tile kt into buffer bf: 5 global_load_lds per thread, zero VALU cvt
  #define STAGE(bf, kt)                                                        \
    do {                                                                       \
      const int k0_ = (kt) * BK;                                               \
      _Pragma("unroll")                                                        \
      for (int j = 0; j < 4; ++j) {                                            \
        const int rr_ = j * 64 + rw;                                           \
        load_lds_16(wb + (size_t)rr_ * 256 + k0_ + wq * 8,                     \
                    &Ws[bf][(j * 256 + t) * 8]);                               \
      }                                                                        \
      load_lds_16(xn + (size_t)rw * 256 + k0_ + wq * 8, &Xs[bf][t * 8]);       \
    } while (0)

  STAGE(0, 0);
  __syncthreads();

  const int qs = (quad ^ ((l16 >> 1) & 3)) * 8;   // read-side swizzle (same involution)

  int cur = 0;
  for (int kt = 0; kt < 8; ++kt) {
    if (kt < 7) STAGE(cur ^ 1, kt + 1);           // prefetch next tile first
    short8 bfr[4];
    #pragma unroll
    for (int nt = 0; nt < 4; ++nt)
      bfr[nt] = *(const short8*)&Xs[cur][(nt * 16 + l16) * BK + qs];
    #pragma unroll
    for (int mt = 0; mt < 4; ++mt) {
      const int rr = wv * 64 + mt * 16 + l16;
      short8 af = *(const short8*)&Ws[cur][rr * BK + qs];
      #pragma unroll
      for (int nt = 0; nt < 4; ++nt)
        acc[mt][nt] = __builtin_amdgcn_mfma_f32_16x16x32_bf16(
            af, bfr[nt], acc[mt][nt], 0, 0, 0);
    }
    __syncthreads();   // drains vmcnt(0): next buffer staged AND this buffer free
    cur ^= 1;
  }
  #undef STAGE

  // epilogue: C/D layout col=lane&15 (n), row=quad*4+reg (m)
  #pragma unroll
  for (int mt = 0; mt < 4; ++mt) {
    const int orow = wv * 64 + mt * 16 + quad * 4;
    #pragma unroll
    for (int nt = 0; nt < 4; ++nt) {
      const int n = nt * 16 + l16;
      #pragma unroll
      for (int rg = 0; rg < 4; ++rg)
        ob[(size_t)(orow + rg) * 3136 + n] = acc[mt][nt][rg];
    }
  }
}

// ============================================================================
// FALLBACK PATH (previous verified kernels, used when workspace is too small)
// ============================================================================

__global__ __launch_bounds__(256) void pool_kernel(const float* __restrict__ x,
                                                   float* __restrict__ pooled) {
  const int bc = blockIdx.x;
  const float4* row = (const float4*)(x + (size_t)bc * 3136);
  const int t = threadIdx.x;
  float s = 0.0f;
  for (int q = t; q < 784; q += 256) {
    float4 v = row[q];
    s += (v.x + v.y) + (v.z + v.w);
  }
  #pragma unroll
  for (int off = 32; off > 0; off >>= 1) s += __shfl_down(s, off, 64);
  __shared__ float red[4];
  if ((t & 63) == 0) red[t >> 6] = s;
  __syncthreads();
  if (t == 0) pooled[bc] = (red[0] + red[1] + red[2] + red[3]) * (1.0f / 3136.0f);
}

__global__ __launch_bounds__(256) void attn_wdyn_kernel(
    const float* __restrict__ pooled, const float* __restrict__ weights,
    const float* __restrict__ w1, const float* __restrict__ b1,
    const float* __restrict__ w2, const float* __restrict__ b2,
    u16* __restrict__ wdyn) {
  const int blk = blockIdx.x;
  const int b = blk >> 3;
  const int oc = blk & 7;
  const int t = threadIdx.x;
  __shared__ float ph[256];
  __shared__ float part[256];
  __shared__ float hb[64];
  __shared__ float lg[8];
  ph[t] = pooled[b * 256 + t];
  __syncthreads();
  {
    const int row = t >> 2, seg = t & 3;
    const float* wr = w1 + row * 256 + seg * 64;
    const float* pp = ph + seg * 64;
    float a = 0.0f;
    #pragma unroll 8
    for (int c = 0; c < 64; ++c) a += pp[c] * wr[c];
    part[t] = a;
  }
  __syncthreads();
  if (t < 64) {
    float a = part[t * 4] + part[t * 4 + 1] + part[t * 4 + 2] + part[t * 4 + 3] + b1[t];
    hb[t] = fmaxf(a, 0.0f);
  }
  __syncthreads();
  if (t < 64) {
    const int row = t >> 3, seg = t & 7;
    const float* wr = w2 + row * 64 + seg * 8;
    float a = 0.0f;
    #pragma unroll
    for (int j = 0; j < 8; ++j) a += hb[seg * 8 + j] * wr[j];
    part[t] = a;
  }
  __syncthreads();
  if (t < 8) {
    float a = b2[t];
    #pragma unroll
    for (int j = 0; j < 8; ++j) a += part[t * 8 + j];
    lg[t] = a;
  }
  __syncthreads();
  float a[8];
  {
    float mx = lg[0];
    #pragma unroll
    for (int e = 1; e < 8; ++e) mx = fmaxf(mx, lg[e]);
    float sum = 0.0f;
    #pragma unroll
    for (int e = 0; e < 8; ++e) { a[e] = __expf(lg[e] - mx); sum += a[e]; }
    float inv = 1.0f / sum;
    #pragma unroll
    for (int e = 0; e < 8; ++e) a[e] *= inv;
  }
  const int o0 = oc * 32;
  for (int i = 0; i < 32; ++i) {
    const int o = o0 + i;
    float acc = 0.0f;
    #pragma unroll
    for (int e = 0; e < 8; ++e)
      acc += a[e] * weights[((size_t)e * 256 + o) * 256 + t];
    wdyn[((size_t)b * 256 + o) * 256 + t] = f32_to_bf16_rne(acc);
  }
}

__global__ __launch_bounds__(256) void dynconv_gemm(const float* __restrict__ x,
                                                    const u16* __restrict__ wdyn,
                                                    float* __restrict__ out) {
  const int nb = blockIdx.x;
  const int b  = blockIdx.y;
  const int t = threadIdx.x;
  const int lane = t & 63;
  const int wv = t >> 6;
  const int quad = lane >> 4;
  const int l16 = lane & 15;

  __shared__ u16 Wf[BM * BK];
  __shared__ u16 Xf[BN * XP];

  const float* xb = x + (size_t)b * (256 * 3136);
  const u16* wb = wdyn + (size_t)b * 256 * 256;
  float* ob = out + (size_t)b * 256 * 3136;
  const int n0 = nb * BN;

  floatx4 acc[4][4];
  #pragma unroll
  for (int i = 0; i < 4; ++i)
    #pragma unroll
    for (int j = 0; j < 4; ++j) acc[i][j] = (floatx4)(0.0f);

  const int xnn = lane;
  const int xkg = wv;

  for (int kt = 0; kt < 8; ++kt) {
    const int k0 = kt * BK;
    #pragma unroll
    for (int j = 0; j < 4; ++j) {
      const int i = j * 256 + t;
      const int r = i >> 2;
      const int c8 = i & 3;
      load_lds_16(wb + r * 256 + k0 + c8 * 8, &Wf[i * 8]);
    }
    {
      const float* xs = xb + (size_t)(k0 + xkg * 8) * 3136 + n0 + xnn;
      float v[8];
      #pragma unroll
      for (int j = 0; j < 8; ++j) v[j] = xs[(size_t)j * 3136];
      short8 pk;
      #pragma unroll
      for (int j = 0; j < 4; ++j) {
        __hip_bfloat162 h2 = __float22bfloat162_rn(make_float2(v[2 * j], v[2 * j + 1]));
        union { __hip_bfloat162 h; struct { short lo, hi; } s; } u; u.h = h2;
        pk[2 * j] = u.s.lo; pk[2 * j + 1] = u.s.hi;
      }
      *(short8*)(&Xf[xnn * XP + xkg * 8]) = pk;
    }
    __syncthreads();
    short8 bfr[4];
    #pragma unroll
    for (int nt = 0; nt < 4; ++nt) {
      const int n = nt * 16 + l16;
      bfr[nt] = *(const short8*)(&Xf[n * XP + quad * 8]);
    }
    #pragma unroll
    for (int mt = 0; mt < 4; ++mt) {
      const int r = wv * 64 + mt * 16 + l16;
      short8 af = *(const short8*)(&Wf[r * BK + quad * 8]);
      #pragma unroll
      for (int nt = 0; nt < 4; ++nt)
        acc[mt][nt] = __builtin_amdgcn_mfma_f32_16x16x32_bf16(
            af, bfr[nt], acc[mt][nt], 0, 0, 0);
    }
    __syncthreads();
  }
  #pragma unroll
  for (int mt = 0; mt < 4; ++mt) {
    const int orow = wv * 64 + mt * 16 + quad * 4;
    #pragma unroll
    for (int nt = 0; nt < 4; ++nt) {
      const int n = n0 + nt * 16 + l16;
      #pragma unroll
      for (int r = 0; r < 4; ++r)
        ob[(size_t)(orow + r) * 3136 + n] = acc[mt][nt][r];
    }
  }
}

// ============================================================================

extern "C" void kernel_launch(void* const* d_in, const int* in_sizes, int n_in,
                              void* d_out, int out_size, void* d_ws, size_t ws_size,
                              hipStream_t stream) {
  const float* x       = (const float*)d_in[0];
  const float* weights = (const float*)d_in[1];
  const float* w1      = (const float*)d_in[2];
  const float* b1      = (const float*)d_in[3];
  const float* w2      = (const float*)d_in[4];
  const float* b2      = (const float*)d_in[5];
  float* out = (float*)d_out;

  const size_t PP_SZ    = (size_t)32 * 49 * 256 * 4;     // 1,605,632 (256-aligned)
  const size_t WDYN_OFF = PP_SZ;
  const size_t WDYN_SZ  = (size_t)32 * 256 * 256 * 2;    // 4,194,304
  const size_t XT_OFF   = WDYN_OFF + WDYN_SZ;            // 5,799,936
  const size_t XT_SZ    = (size_t)32 * 3136 * 256 * 2;   // 51,380,224
  const size_t NEED     = XT_OFF + XT_SZ;                // ~57.2 MB

  if (ws_size >= NEED) {
    float* pp = (float*)d_ws;
    u16* wdyn = (u16*)((char*)d_ws + WDYN_OFF);
    u16* xT   = (u16*)((char*)d_ws + XT_OFF);
    transpose_pool_kernel<<<dim3(49, 32), 256, 0, stream>>>(x, xT, pp);
    attn_wdyn_kernel2<<<256, 256, 0, stream>>>(pp, weights, w1, b1, w2, b2, wdyn);
    dynconv_gemm2<<<dim3(49, 32), 256, 0, stream>>>(xT, wdyn, out);
  } else {
    float* pooled = (float*)d_ws;                 // 32 KB
    u16* wdyn = (u16*)((char*)d_ws + 32768);      // 4 MB
    pool_kernel<<<8192, 256, 0, stream>>>(x, pooled);
    attn_wdyn_kernel<<<256, 256, 0, stream>>>(pooled, weights, w1, b1, w2, b2, wdyn);
    dynconv_gemm<<<dim3(49, 32), 256, 0, stream>>>(x, wdyn, out);
  }
}

// Round 2
// 235.651 us; speedup vs baseline: 1.0375x; 1.0375x over previous
//
#include <hip/hip_runtime.h>
#include <hip/hip_bf16.h>

typedef unsigned short u16;
typedef __attribute__((ext_vector_type(8))) short short8;
typedef __attribute__((ext_vector_type(4))) float floatx4;

__device__ __forceinline__ u16 f32_to_bf16_rne(float f) {
  union { float f; unsigned int u; } v; v.f = f;
  unsigned int u = v.u;
  u += 0x7FFFu + ((u >> 16) & 1u);
  return (u16)(u >> 16);
}

// ---------------- Kernel 1: global average pool ----------------
// grid 8192 = B*C blocks, 256 threads. pooled[b*256+c] = mean over 3136.
// Side effect: streams all of x -> x becomes L3-resident for the GEMM.
__global__ __launch_bounds__(256) void pool_kernel(const float* __restrict__ x,
                                                   float* __restrict__ pooled) {
  const int bc = blockIdx.x;
  const float4* row = (const float4*)(x + (size_t)bc * 3136);
  const int t = threadIdx.x;
  float s = 0.0f;
  for (int q = t; q < 784; q += 256) {   // 784 float4 = 3136 floats
    float4 v = row[q];
    s += (v.x + v.y) + (v.z + v.w);
  }
  #pragma unroll
  for (int off = 32; off > 0; off >>= 1) s += __shfl_down(s, off, 64);
  __shared__ float red[4];
  if ((t & 63) == 0) red[t >> 6] = s;
  __syncthreads();
  if (t == 0) pooled[bc] = (red[0] + red[1] + red[2] + red[3]) * (1.0f / 3136.0f);
}

// ---------------- Kernel 2: attention MLP + w_dyn (bf16) ----------------
__global__ __launch_bounds__(256) void attn_wdyn_kernel(
    const float* __restrict__ pooled, const float* __restrict__ weights,
    const float* __restrict__ w1, const float* __restrict__ b1,
    const float* __restrict__ w2, const float* __restrict__ b2,
    u16* __restrict__ wdyn) {
  const int blk = blockIdx.x;
  const int b = blk >> 3;
  const int oc = blk & 7;
  const int t = threadIdx.x;
  __shared__ float ph[256];
  __shared__ float part[256];
  __shared__ float hb[64];
  __shared__ float lg[8];
  ph[t] = pooled[b * 256 + t];
  __syncthreads();
  {
    const int row = t >> 2, seg = t & 3;
    const float* wr = w1 + row * 256 + seg * 64;
    const float* pp = ph + seg * 64;
    float a = 0.0f;
    #pragma unroll 8
    for (int c = 0; c < 64; ++c) a += pp[c] * wr[c];
    part[t] = a;
  }
  __syncthreads();
  if (t < 64) {
    float a = part[t * 4] + part[t * 4 + 1] + part[t * 4 + 2] + part[t * 4 + 3] + b1[t];
    hb[t] = fmaxf(a, 0.0f);
  }
  __syncthreads();
  if (t < 64) {
    const int row = t >> 3, seg = t & 7;
    const float* wr = w2 + row * 64 + seg * 8;
    float a = 0.0f;
    #pragma unroll
    for (int j = 0; j < 8; ++j) a += hb[seg * 8 + j] * wr[j];
    part[t] = a;
  }
  __syncthreads();
  if (t < 8) {
    float a = b2[t];
    #pragma unroll
    for (int j = 0; j < 8; ++j) a += part[t * 8 + j];
    lg[t] = a;
  }
  __syncthreads();
  float a[8];
  {
    float mx = lg[0];
    #pragma unroll
    for (int e = 1; e < 8; ++e) mx = fmaxf(mx, lg[e]);
    float sum = 0.0f;
    #pragma unroll
    for (int e = 0; e < 8; ++e) { a[e] = __expf(lg[e] - mx); sum += a[e]; }
    float inv = 1.0f / sum;
    #pragma unroll
    for (int e = 0; e < 8; ++e) a[e] *= inv;
  }
  const int o0 = oc * 32;
  for (int i = 0; i < 32; ++i) {
    const int o = o0 + i;
    float acc = 0.0f;
    #pragma unroll
    for (int e = 0; e < 8; ++e)
      acc += a[e] * weights[((size_t)e * 256 + o) * 256 + t];
    wdyn[((size_t)b * 256 + o) * 256 + t] = f32_to_bf16_rne(acc);
  }
}

// ---------------- Kernel 3: batched GEMM out[b] = Wdyn[b] @ X[b] -------------
// M=256, N=3136 (spatial), K=256. Tile 256x64x32, 4 waves, 16x16x32 MFMA.
// v3 structure:
//  - A (Wdyn) fragments loaded DIRECTLY global->VGPR (L2-resident 131 KB),
//    prefetched one K-tile ahead. No W LDS staging, no W ds_reads.
//  - B (X) staged f32->bf16 into double-buffered LDS, XOR chunk swizzle,
//    loads issued before MFMA (async-split), ONE barrier per K-step.
#define BK 32

__global__ __launch_bounds__(256) void dynconv_gemm3(
    const float* __restrict__ x, const u16* __restrict__ wdyn,
    float* __restrict__ out) {
  const int nb = blockIdx.x;   // 0..48
  const int b  = blockIdx.y;   // 0..31
  const int t = threadIdx.x;
  const int lane = t & 63;
  const int wv = t >> 6;
  const int quad = lane >> 4;
  const int l16 = lane & 15;
  const int n0 = nb * 64;

  __shared__ __align__(16) u16 Xs[2][64 * BK];   // 2 x 4 KB

  const float* xb = x + (size_t)b * (256 * 3136) + n0 + lane;  // column for this lane
  const u16* wb = wdyn + (size_t)b * 65536;
  float* ob = out + (size_t)b * (256 * 3136) + n0;

  // A-frag base: row wv*64 + l16 (+ mt*16), k-chunk quad*8 (+ k0)
  const u16* wfp = wb + (size_t)(wv * 64 + l16) * 256 + quad * 8;

  // X LDS chunk swizzle (same involution write & read): key = (row>>1)&3
  const int wchunk = (wv ^ ((lane >> 1) & 3)) * 8;     // write: row=lane, chunk=wv
  const int rchunk = (quad ^ ((l16 >> 1) & 3)) * 8;    // read: row=nt*16+l16, chunk=quad

  floatx4 acc[4][4];
  #pragma unroll
  for (int i = 0; i < 4; ++i)
    #pragma unroll
    for (int j = 0; j < 4; ++j) acc[i][j] = (floatx4)(0.0f);

  // ---- prologue: tile 0 ----
  short8 wcur[4];
  #pragma unroll
  for (int mt = 0; mt < 4; ++mt)
    wcur[mt] = *(const short8*)(wfp + mt * 16 * 256);
  {
    float xr[8];
    #pragma unroll
    for (int j = 0; j < 8; ++j) xr[j] = xb[(size_t)(wv * 8 + j) * 3136];
    short8 pk;
    #pragma unroll
    for (int j = 0; j < 4; ++j) {
      __hip_bfloat162 h2 = __float22bfloat162_rn(make_float2(xr[2 * j], xr[2 * j + 1]));
      union { __hip_bfloat162 h; struct { short lo, hi; } s; } u; u.h = h2;
      pk[2 * j] = u.s.lo; pk[2 * j + 1] = u.s.hi;
    }
    *(short8*)(&Xs[0][lane * BK + wchunk]) = pk;
  }
  __syncthreads();

  int cur = 0;
  for (int kt = 0; kt < 8; ++kt) {
    // ---- issue next tile's loads BEFORE compute (latency hides under MFMA) ----
    short8 wnxt[4];
    float xr[8];
    if (kt < 7) {
      const int k1 = (kt + 1) * BK;
      #pragma unroll
      for (int j = 0; j < 8; ++j) xr[j] = xb[(size_t)(k1 + wv * 8 + j) * 3136];
      #pragma unroll
      for (int mt = 0; mt < 4; ++mt)
        wnxt[mt] = *(const short8*)(wfp + mt * 16 * 256 + k1);
    }
    // ---- MFMA on current tile (A from regs, B from LDS) ----
    short8 bfr[4];
    #pragma unroll
    for (int nt = 0; nt < 4; ++nt)
      bfr[nt] = *(const short8*)(&Xs[cur][(nt * 16 + l16) * BK + rchunk]);
    #pragma unroll
    for (int mt = 0; mt < 4; ++mt)
      #pragma unroll
      for (int nt = 0; nt < 4; ++nt)
        acc[mt][nt] = __builtin_amdgcn_mfma_f32_16x16x32_bf16(
            wcur[mt], bfr[nt], acc[mt][nt], 0, 0, 0);
    // ---- stage next X tile (cvt + LDS write), rotate A prefetch ----
    if (kt < 7) {
      short8 pk;
      #pragma unroll
      for (int j = 0; j < 4; ++j) {
        __hip_bfloat162 h2 = __float22bfloat162_rn(make_float2(xr[2 * j], xr[2 * j + 1]));
        union { __hip_bfloat162 h; struct { short lo, hi; } s; } u; u.h = h2;
        pk[2 * j] = u.s.lo; pk[2 * j + 1] = u.s.hi;
      }
      *(short8*)(&Xs[cur ^ 1][lane * BK + wchunk]) = pk;
      #pragma unroll
      for (int mt = 0; mt < 4; ++mt) wcur[mt] = wnxt[mt];
    }
    __syncthreads();
    cur ^= 1;
  }

  // ---- epilogue: C/D layout col=lane&15 (n), row=quad*4+reg (m) ----
  #pragma unroll
  for (int mt = 0; mt < 4; ++mt) {
    const int orow = wv * 64 + mt * 16 + quad * 4;
    #pragma unroll
    for (int nt = 0; nt < 4; ++nt) {
      const int n = nt * 16 + l16;
      #pragma unroll
      for (int rg = 0; rg < 4; ++rg)
        ob[(size_t)(orow + rg) * 3136 + n] = acc[mt][nt][rg];
    }
  }
}

extern "C" void kernel_launch(void* const* d_in, const int* in_sizes, int n_in,
                              void* d_out, int out_size, void* d_ws, size_t ws_size,
                              hipStream_t stream) {
  const float* x       = (const float*)d_in[0];
  const float* weights = (const float*)d_in[1];
  const float* w1      = (const float*)d_in[2];
  const float* b1      = (const float*)d_in[3];
  const float* w2      = (const float*)d_in[4];
  const float* b2      = (const float*)d_in[5];
  float* out = (float*)d_out;

  float* pooled = (float*)d_ws;                       // 32 KB
  u16* wdyn = (u16*)((char*)d_ws + 32768);            // 4 MB bf16 [32][256][256]

  pool_kernel<<<8192, 256, 0, stream>>>(x, pooled);
  attn_wdyn_kernel<<<256, 256, 0, stream>>>(pooled, weights, w1, b1, w2, b2, wdyn);
  dynconv_gemm3<<<dim3(49, 32), 256, 0, stream>>>(x, wdyn, out);
}